// Round 1
// baseline (1010.615 us; speedup 1.0000x reference)
//
#include <hip/hip_runtime.h>

#define NN 50000
#define NE 800000

// ---------------------------------------------------------------- utilities
__global__ void zero_int_kernel(int* __restrict__ p, int n) {
    int i = blockIdx.x * blockDim.x + threadIdx.x;
    if (i < n) p[i] = 0;
}

// ---------------------------------------------------------------- CSR build
__global__ void deg_kernel(const int* __restrict__ dst, int* __restrict__ deg, int E) {
    int e = blockIdx.x * blockDim.x + threadIdx.x;
    if (e < E) atomicAdd(&deg[dst[e]], 1);
}

// single-block exclusive scan over deg[0..n-1]; writes row_start[0..n] and cursor copy
__global__ void scan_kernel(const int* __restrict__ deg, int* __restrict__ row_start,
                            int* __restrict__ cursor, int n) {
    __shared__ int part[1024];
    int t = threadIdx.x;
    int chunk = (n + 1023) / 1024;
    int lo = t * chunk;
    int hi = lo + chunk; if (hi > n) hi = n; if (lo > n) lo = n;
    int s = 0;
    for (int i = lo; i < hi; ++i) s += deg[i];
    part[t] = s;
    __syncthreads();
    for (int off = 1; off < 1024; off <<= 1) {
        int v = (t >= off) ? part[t - off] : 0;
        __syncthreads();
        part[t] += v;
        __syncthreads();
    }
    int run = (t == 0) ? 0 : part[t - 1];
    for (int i = lo; i < hi; ++i) {
        row_start[i] = run;
        cursor[i] = run;
        run += deg[i];
    }
    if (t == 1023) row_start[n] = run;
}

__global__ void fill_kernel(const int* __restrict__ src, const int* __restrict__ dst,
                            int* __restrict__ cursor, int* __restrict__ csr_src,
                            int* __restrict__ csr_eid, int E) {
    int e = blockIdx.x * blockDim.x + threadIdx.x;
    if (e < E) {
        int d = dst[e];
        int p = atomicAdd(&cursor[d], 1);
        csr_src[p] = src[e];
        csr_eid[p] = e;
    }
}

// ---------------------------------------------------------------- agg_e (once)
// thread per node; 8 feats in regs
__global__ void agge_kernel(const float* __restrict__ ea, const int* __restrict__ row_start,
                            const int* __restrict__ eid, float* __restrict__ aggE) {
    int v = blockIdx.x * blockDim.x + threadIdx.x;
    if (v >= NN) return;
    float4 a0 = {0.f, 0.f, 0.f, 0.f}, a1 = {0.f, 0.f, 0.f, 0.f};
    int lo = row_start[v], hi = row_start[v + 1];
    for (int j = lo; j < hi; ++j) {
        int e = eid[j];
        const float4* p = reinterpret_cast<const float4*>(ea + (size_t)e * 8);
        float4 u = p[0], w = p[1];
        a0.x += u.x; a0.y += u.y; a0.z += u.z; a0.w += u.w;
        a1.x += w.x; a1.y += w.y; a1.z += w.z; a1.w += w.w;
    }
    float4* o = reinterpret_cast<float4*>(aggE + (size_t)v * 8);
    o[0] = a0; o[1] = a1;
}

// ---------------------------------------------------------------- agg_h (per layer)
// wave per node, no atomics
template <int DIN>
__global__ void aggh_kernel(const float* __restrict__ h, const int* __restrict__ row_start,
                            const int* __restrict__ csrc, float* __restrict__ aggH) {
    int w = blockIdx.x * (blockDim.x >> 6) + (threadIdx.x >> 6);
    int lane = threadIdx.x & 63;
    if (w >= NN) return;
    int lo = row_start[w], hi = row_start[w + 1];
    if constexpr (DIN == 128) {
        float2 acc = {0.f, 0.f};
        const float2* H = reinterpret_cast<const float2*>(h);
        for (int j = lo; j < hi; ++j) {
            int s = csrc[j];
            float2 v = H[(size_t)s * 64 + lane];
            acc.x += v.x; acc.y += v.y;
        }
        reinterpret_cast<float2*>(aggH)[(size_t)w * 64 + lane] = acc;
    } else if constexpr (DIN == 64) {
        float acc = 0.f;
        for (int j = lo; j < hi; ++j) {
            int s = csrc[j];
            acc += h[(size_t)s * 64 + lane];
        }
        aggH[(size_t)w * 64 + lane] = acc;
    } else {  // DIN == 32
        if (lane < 32) {
            float acc = 0.f;
            for (int j = lo; j < hi; ++j) {
                int s = csrc[j];
                acc += h[(size_t)s * 32 + lane];
            }
            aggH[(size_t)w * 32 + lane] = acc;
        }
    }
}

// ---------------------------------------------------------------- fused dense layer
// out[n,:] = relu( h[n,:]@Ws + aggH[n,:]@Wm[0:DIN] + aggE[n,:]@Wm[DIN:DIN+8] + b )
// block: 256 threads, tile 64 rows x DOUT cols; thread = 4 rows x (DOUT/16) cols
template <int DIN, int DOUT>
__global__ __launch_bounds__(256) void dense_kernel(
    const float* __restrict__ h, const float* __restrict__ aggH, const float* __restrict__ aggE,
    const float* __restrict__ Ws, const float* __restrict__ Wm, const float* __restrict__ b,
    float* __restrict__ out) {
    constexpr int K = 2 * DIN + 8;
    constexpr int TN = DOUT / 16;
    __shared__ float Xs[8][65];          // [k][row], padded to dodge bank conflicts
    __shared__ float Wsh[8][DOUT];       // [k][col]
    int t = threadIdx.x;
    int tn = t & 15, tm = t >> 4;
    int row0 = blockIdx.x * 64;

    float acc[4][TN];
#pragma unroll
    for (int r = 0; r < 4; ++r)
#pragma unroll
        for (int c = 0; c < TN; ++c) acc[r][c] = 0.f;

    for (int k0 = 0; k0 < K; k0 += 8) {
        // stage X: 64 rows x 8 k  (lane t reads row t/8, k t%8 -> 32B-coalesced)
#pragma unroll
        for (int rep = 0; rep < 2; ++rep) {
            int idx = t + rep * 256;
            int r = idx >> 3, k = idx & 7;
            int row = row0 + r, kk = k0 + k;
            float v = 0.f;
            if (row < NN) {
                if (kk < DIN)            v = h[(size_t)row * DIN + kk];
                else if (kk < 2 * DIN)   v = aggH[(size_t)row * DIN + (kk - DIN)];
                else                     v = aggE[(size_t)row * 8 + (kk - 2 * DIN)];
            }
            Xs[k][r] = v;
        }
        // stage W: 8 x DOUT (coalesced)
#pragma unroll
        for (int idx = t; idx < 8 * DOUT; idx += 256) {
            int k = idx / DOUT, c = idx % DOUT;
            int kk = k0 + k;
            float v = (kk < DIN) ? Ws[(size_t)kk * DOUT + c]
                                 : Wm[(size_t)(kk - DIN) * DOUT + c];
            Wsh[k][c] = v;
        }
        __syncthreads();
#pragma unroll
        for (int k = 0; k < 8; ++k) {
            float xv[4];
#pragma unroll
            for (int r = 0; r < 4; ++r) xv[r] = Xs[k][tm * 4 + r];
            float wv[TN];
#pragma unroll
            for (int c = 0; c < TN; ++c) wv[c] = Wsh[k][tn * TN + c];
#pragma unroll
            for (int r = 0; r < 4; ++r)
#pragma unroll
                for (int c = 0; c < TN; ++c) acc[r][c] += xv[r] * wv[c];
        }
        __syncthreads();
    }
    // epilogue: bias + relu + store
#pragma unroll
    for (int r = 0; r < 4; ++r) {
        int row = row0 + tm * 4 + r;
        if (row < NN) {
#pragma unroll
            for (int c = 0; c < TN; ++c) {
                int col = tn * TN + c;
                float v = acc[r][c] + b[col];
                out[(size_t)row * DOUT + col] = v > 0.f ? v : 0.f;
            }
        }
    }
}

// ---------------------------------------------------------------- final linear
__global__ void final_kernel(const float* __restrict__ h, const float* __restrict__ Wc,
                             const float* __restrict__ bc, float* __restrict__ out) {
    int w = blockIdx.x * (blockDim.x >> 6) + (threadIdx.x >> 6);
    int lane = threadIdx.x & 63;
    if (w >= NN) return;
    const float2* H = reinterpret_cast<const float2*>(h);
    const float2* W = reinterpret_cast<const float2*>(Wc);
    float2 hv = H[(size_t)w * 64 + lane];
    float2 wv = W[lane];
    float p = hv.x * wv.x + hv.y * wv.y;
#pragma unroll
    for (int off = 32; off; off >>= 1) p += __shfl_down(p, off);
    if (lane == 0) out[w] = p + bc[0];
}

// ---------------------------------------------------------------- launch
extern "C" void kernel_launch(void* const* d_in, const int* in_sizes, int n_in,
                              void* d_out, int out_size, void* d_ws, size_t ws_size,
                              hipStream_t stream) {
    const float* x   = (const float*)d_in[0];
    const float* ea  = (const float*)d_in[1];
    const int*   src = (const int*)d_in[2];
    const int*   dst = (const int*)d_in[3];
    const float* Ws[5]; const float* Wm[5]; const float* bb[5];
    for (int i = 0; i < 5; ++i) {
        Ws[i] = (const float*)d_in[4 + 3 * i];
        Wm[i] = (const float*)d_in[5 + 3 * i];
        bb[i] = (const float*)d_in[6 + 3 * i];
    }
    const float* Wc = (const float*)d_in[19];
    const float* bc = (const float*)d_in[20];
    float* out = (float*)d_out;

    size_t off = 0;
    auto alloc = [&](size_t bytes) {
        void* p = (char*)d_ws + off;
        off += (bytes + 255) & ~(size_t)255;
        return p;
    };
    float* hA        = (float*)alloc((size_t)NN * 128 * 4);
    float* hB        = (float*)alloc((size_t)NN * 128 * 4);
    float* aggH      = (float*)alloc((size_t)NN * 128 * 4);
    float* aggE      = (float*)alloc((size_t)NN * 8 * 4);
    int*   deg       = (int*)alloc((size_t)(NN + 1) * 4);
    int*   row_start = (int*)alloc((size_t)(NN + 1) * 4);
    int*   cursor    = (int*)alloc((size_t)NN * 4);
    int*   csr_src   = (int*)alloc((size_t)NE * 4);
    int*   csr_eid   = (int*)alloc((size_t)NE * 4);
    (void)ws_size; (void)in_sizes; (void)n_in; (void)out_size;

    // CSR build (per launch — no cached state)
    zero_int_kernel<<<(NN + 1 + 255) / 256, 256, 0, stream>>>(deg, NN + 1);
    deg_kernel<<<(NE + 255) / 256, 256, 0, stream>>>(dst, deg, NE);
    scan_kernel<<<1, 1024, 0, stream>>>(deg, row_start, cursor, NN);
    fill_kernel<<<(NE + 255) / 256, 256, 0, stream>>>(src, dst, cursor, csr_src, csr_eid, NE);

    // edge-attr aggregation (layer-independent)
    agge_kernel<<<(NN + 255) / 256, 256, 0, stream>>>(ea, row_start, csr_eid, aggE);

    const int GRID_W = (NN + 3) / 4;       // wave-per-node kernels (4 waves/block)
    const int GRID_D = (NN + 63) / 64;     // dense kernels

    // layer 0: 32 -> 64
    aggh_kernel<32><<<GRID_W, 256, 0, stream>>>(x, row_start, csr_src, aggH);
    dense_kernel<32, 64><<<GRID_D, 256, 0, stream>>>(x, aggH, aggE, Ws[0], Wm[0], bb[0], hA);
    // layer 1: 64 -> 128
    aggh_kernel<64><<<GRID_W, 256, 0, stream>>>(hA, row_start, csr_src, aggH);
    dense_kernel<64, 128><<<GRID_D, 256, 0, stream>>>(hA, aggH, aggE, Ws[1], Wm[1], bb[1], hB);
    // layer 2: 128 -> 128
    aggh_kernel<128><<<GRID_W, 256, 0, stream>>>(hB, row_start, csr_src, aggH);
    dense_kernel<128, 128><<<GRID_D, 256, 0, stream>>>(hB, aggH, aggE, Ws[2], Wm[2], bb[2], hA);
    // layer 3: 128 -> 128
    aggh_kernel<128><<<GRID_W, 256, 0, stream>>>(hA, row_start, csr_src, aggH);
    dense_kernel<128, 128><<<GRID_D, 256, 0, stream>>>(hA, aggH, aggE, Ws[3], Wm[3], bb[3], hB);
    // layer 4: 128 -> 128
    aggh_kernel<128><<<GRID_W, 256, 0, stream>>>(hB, row_start, csr_src, aggH);
    dense_kernel<128, 128><<<GRID_D, 256, 0, stream>>>(hB, aggH, aggE, Ws[4], Wm[4], bb[4], hA);

    // readout
    final_kernel<<<GRID_W, 256, 0, stream>>>(hA, Wc, bc, out);
}